// Round 1
// baseline (1190.351 us; speedup 1.0000x reference)
//
#include <hip/hip_runtime.h>
#include <float.h>
#include <math.h>

// BatchHardTripletLoss on MI355X.
// batch = concat(h1,h2) : [4096,512] fp32.
// hardest_positive[i] = dist(i, i^partner) (exactly one positive pair per row)
// hardest_negative[i] = min_{j: j%2048 != i%2048} dist(i,j)
// outputs: [loss, mean(diff), good, bad, sqrt(mean(sq))]

#define NTOT 4096
#define NHALF 2048
#define DIM 512
#define BM 128
#define BK 32
#define NTILE (NTOT / BM)   // 32
#define KTILES (DIM / BK)   // 16
#define FLTMAX 3.402823466e+38f

__device__ __forceinline__ const float* row_ptr(const float* h1, const float* h2, int row) {
    return (row < NHALF) ? (h1 + (size_t)row * DIM) : (h2 + (size_t)(row - NHALF) * DIM);
}

__global__ void init_kernel(unsigned int* __restrict__ minb) {
    int i = blockIdx.x * blockDim.x + threadIdx.x;
    if (i < NTOT) minb[i] = 0x7F800000u;  // +inf bits
}

// One wave per row i in [0,2048): sq[i], sq[i+2048], partner d2 (gram form to match ref).
__global__ __launch_bounds__(256) void rowstats_kernel(const float* __restrict__ h1,
                                                       const float* __restrict__ h2,
                                                       float* __restrict__ sq,
                                                       float* __restrict__ hp_d2) {
    int wv = threadIdx.x >> 6;
    int lane = threadIdx.x & 63;
    int i = blockIdx.x * 4 + wv;
    if (i >= NHALF) return;
    const float4* r1 = (const float4*)(h1 + (size_t)i * DIM);
    const float4* r2 = (const float4*)(h2 + (size_t)i * DIM);
    float4 a0 = r1[lane], a1 = r1[lane + 64];
    float4 b0 = r2[lane], b1 = r2[lane + 64];
    float s1 = a0.x*a0.x + a0.y*a0.y + a0.z*a0.z + a0.w*a0.w
             + a1.x*a1.x + a1.y*a1.y + a1.z*a1.z + a1.w*a1.w;
    float s2 = b0.x*b0.x + b0.y*b0.y + b0.z*b0.z + b0.w*b0.w
             + b1.x*b1.x + b1.y*b1.y + b1.z*b1.z + b1.w*b1.w;
    float s12 = a0.x*b0.x + a0.y*b0.y + a0.z*b0.z + a0.w*b0.w
              + a1.x*b1.x + a1.y*b1.y + a1.z*b1.z + a1.w*b1.w;
    #pragma unroll
    for (int m = 1; m < 64; m <<= 1) {
        s1  += __shfl_xor(s1, m);
        s2  += __shfl_xor(s2, m);
        s12 += __shfl_xor(s12, m);
    }
    if (lane == 0) {
        sq[i] = s1;
        sq[i + NHALF] = s2;
        float pd = s1 + s2 - 2.0f * s12;
        hp_d2[i] = pd;
        hp_d2[i + NHALF] = pd;
    }
}

// Tiled gram with fused row-min and col-min (symmetric: only bi<=bj tiles run).
// 256 threads (16x16), TM=TN=8, BM=BN=128, BK=32. LDS float4-chunk layout,
// XOR swizzle on (row>>3)&7 (lanes within one ds_read differ in row>>3).
__global__ __launch_bounds__(256) void pairmin_kernel(const float* __restrict__ h1,
                                                      const float* __restrict__ h2,
                                                      const float* __restrict__ sq,
                                                      unsigned int* __restrict__ minb) {
    int bi = blockIdx.y, bj = blockIdx.x;
    if (bj < bi) return;  // upper triangle incl. diagonal

    __shared__ float4 As[BM * 8];   // [row][chunk^((row>>3)&7)], 16KB
    __shared__ float4 Bs[BM * 8];   // 16KB
    __shared__ float colbuf[BM][4]; // per-wave column partial mins, 2KB

    int tid = threadIdx.x;
    int tx = tid & 15, ty = tid >> 4;
    int lane = tid & 63, wv = tid >> 6;

    float acc[8][8];
    #pragma unroll
    for (int r = 0; r < 8; ++r)
        #pragma unroll
        for (int c = 0; c < 8; ++c) acc[r][c] = 0.0f;

    int rowA0 = bi * BM, rowB0 = bj * BM;

    for (int kt = 0; kt < KTILES; ++kt) {
        int k0 = kt * BK;
        __syncthreads();
        #pragma unroll
        for (int s = 0; s < 4; ++s) {
            int q = tid + s * 256;           // 1024 chunks per tile
            int r = q >> 3, ci = q & 7;
            int sw = ci ^ ((r >> 3) & 7);
            const float* pa = row_ptr(h1, h2, rowA0 + r) + k0 + ci * 4;
            As[r * 8 + sw] = *(const float4*)pa;
            const float* pb = row_ptr(h1, h2, rowB0 + r) + k0 + ci * 4;
            Bs[r * 8 + sw] = *(const float4*)pb;
        }
        __syncthreads();
        #pragma unroll
        for (int kc = 0; kc < 8; ++kc) {
            float4 av[8], bv[8];
            #pragma unroll
            for (int r = 0; r < 8; ++r) {
                int ar = ty * 8 + r;
                av[r] = As[ar * 8 + (kc ^ ((ar >> 3) & 7))];
                int bc = tx * 8 + r;
                bv[r] = Bs[bc * 8 + (kc ^ ((bc >> 3) & 7))];
            }
            #pragma unroll
            for (int r = 0; r < 8; ++r)
                #pragma unroll
                for (int c = 0; c < 8; ++c)
                    acc[r][c] += av[r].x * bv[c].x + av[r].y * bv[c].y
                               + av[r].z * bv[c].z + av[r].w * bv[c].w;
        }
    }

    // Epilogue: d2 = sq_i + sq_j - 2*dot; mask same-label (j%2048 == i%2048).
    float sqi[8], sqj[8];
    #pragma unroll
    for (int r = 0; r < 8; ++r) sqi[r] = sq[rowA0 + ty * 8 + r];
    #pragma unroll
    for (int c = 0; c < 8; ++c) sqj[c] = sq[rowB0 + tx * 8 + c];

    float rmin[8], cmin[8];
    #pragma unroll
    for (int r = 0; r < 8; ++r) rmin[r] = FLTMAX;
    #pragma unroll
    for (int c = 0; c < 8; ++c) cmin[c] = FLTMAX;

    #pragma unroll
    for (int r = 0; r < 8; ++r) {
        int gi = rowA0 + ty * 8 + r;
        #pragma unroll
        for (int c = 0; c < 8; ++c) {
            int gj = rowB0 + tx * 8 + c;
            float d2 = sqi[r] + sqj[c] - 2.0f * acc[r][c];
            d2 = fmaxf(d2, 0.0f);                    // keeps uint-bit ordering valid
            if (((gi - gj) & (NHALF - 1)) == 0) d2 = FLTMAX;  // same label or diag
            rmin[r] = fminf(rmin[r], d2);
            cmin[c] = fminf(cmin[c], d2);
        }
    }

    // Row mins: reduce across tx (lane bits 0..3), tx==0 lanes commit.
    #pragma unroll
    for (int m = 1; m <= 8; m <<= 1) {
        #pragma unroll
        for (int r = 0; r < 8; ++r) rmin[r] = fminf(rmin[r], __shfl_xor(rmin[r], m));
    }
    if (tx == 0) {
        #pragma unroll
        for (int r = 0; r < 8; ++r)
            atomicMin(&minb[rowA0 + ty * 8 + r], __float_as_uint(rmin[r]));
    }

    // Col mins: reduce across ty-within-wave (lane bits 4,5), then cross-wave via LDS.
    #pragma unroll
    for (int m = 16; m <= 32; m <<= 1) {
        #pragma unroll
        for (int c = 0; c < 8; ++c) cmin[c] = fminf(cmin[c], __shfl_xor(cmin[c], m));
    }
    if (lane < 16) {
        #pragma unroll
        for (int c = 0; c < 8; ++c) colbuf[lane * 8 + c][wv] = cmin[c];
    }
    __syncthreads();
    if (tid < BM) {
        float m = fminf(fminf(colbuf[tid][0], colbuf[tid][1]),
                        fminf(colbuf[tid][2], colbuf[tid][3]));
        atomicMin(&minb[rowB0 + tid], __float_as_uint(m));
    }
}

__global__ __launch_bounds__(256) void finalize_kernel(const float* __restrict__ sq,
                                                       const float* __restrict__ hp_d2,
                                                       const unsigned int* __restrict__ minb,
                                                       float* __restrict__ out) {
    __shared__ float red[5][256];
    int tid = threadIdx.x;
    float sum_diff = 0.f, sum_rel = 0.f, sum_sq = 0.f, cnt_rel = 0.f, cnt_good = 0.f;
    for (int i = tid; i < NTOT; i += 256) {
        float hn = fmaxf(sqrtf(fmaxf(__uint_as_float(minb[i]), 1e-14f)), 1e-7f);
        float hp = fmaxf(sqrtf(fmaxf(hp_d2[i], 1e-14f)), 1e-7f);
        float diff = hp - hn;
        float t = fmaxf(diff + 0.1f, 0.0f);
        sum_diff += diff;
        sum_sq += sq[i];
        if (t < 1e-5f) cnt_good += 1.0f;
        if (t > 1e-5f) { cnt_rel += 1.0f; sum_rel += t; }
    }
    red[0][tid] = sum_diff; red[1][tid] = sum_rel; red[2][tid] = sum_sq;
    red[3][tid] = cnt_rel;  red[4][tid] = cnt_good;
    __syncthreads();
    for (int s = 128; s > 0; s >>= 1) {
        if (tid < s) {
            #pragma unroll
            for (int q = 0; q < 5; ++q) red[q][tid] += red[q][tid + s];
        }
        __syncthreads();
    }
    if (tid == 0) {
        float nrel = fmaxf(red[3][0], 1.0f);
        out[0] = red[1][0] / nrel;                 // loss (mean over relevant)
        out[1] = red[0][0] / (float)NTOT;          // mean(differences)
        out[2] = red[4][0];                        // good
        out[3] = (float)NTOT - red[4][0];          // bad
        out[4] = sqrtf(red[2][0] / (float)NTOT);   // sqrt(mean norm^2)
    }
}

extern "C" void kernel_launch(void* const* d_in, const int* in_sizes, int n_in,
                              void* d_out, int out_size, void* d_ws, size_t ws_size,
                              hipStream_t stream) {
    const float* h1 = (const float*)d_in[0];
    const float* h2 = (const float*)d_in[1];
    // d_in[2] (h3) is unused by the reference.

    float* sq = (float*)d_ws;                       // [4096]
    float* hp_d2 = sq + NTOT;                       // [4096]
    unsigned int* minb = (unsigned int*)(hp_d2 + NTOT);  // [4096]
    float* out = (float*)d_out;

    init_kernel<<<NTOT / 256, 256, 0, stream>>>(minb);
    rowstats_kernel<<<NHALF / 4, 256, 0, stream>>>(h1, h2, sq, hp_d2);
    dim3 grid(NTILE, NTILE);
    pairmin_kernel<<<grid, 256, 0, stream>>>(h1, h2, sq, minb);
    finalize_kernel<<<1, 256, 0, stream>>>(sq, hp_d2, minb, out);
}

// Round 2
// 230.021 us; speedup vs baseline: 5.1750x; 5.1750x over previous
//
#include <hip/hip_runtime.h>
#include <float.h>
#include <math.h>

// BatchHardTripletLoss on MI355X (fp32 VALU path, symmetric triangular tiling).
// batch = concat(h1,h2) : [4096,512] fp32.
// hardest_positive[i] = dist(i, partner(i))  (exactly one positive per row)
// hardest_negative[i] = min_{j: j%2048 != i%2048} dist(i,j)
// outputs: [loss, mean(diff), good, bad, sqrt(mean(sq))]

#define NTOT 4096
#define NHALF 2048
#define DIM 512
#define BM 128
#define BK 32
#define NTILE (NTOT / BM)            // 32
#define NTRI (NTILE * (NTILE + 1) / 2)  // 528
#define KTILES (DIM / BK)            // 16
#define FLTMAX 3.402823466e+38f

__global__ void init_kernel(unsigned int* __restrict__ minb) {
    int i = blockIdx.x * blockDim.x + threadIdx.x;
    if (i < NTOT) minb[i] = 0x7F800000u;  // +inf bits
}

// One wave per row i in [0,2048): sq[i], sq[i+2048], partner d2 (gram form, matches ref).
__global__ __launch_bounds__(256) void rowstats_kernel(const float* __restrict__ h1,
                                                       const float* __restrict__ h2,
                                                       float* __restrict__ sq,
                                                       float* __restrict__ hp_d2) {
    int wv = threadIdx.x >> 6;
    int lane = threadIdx.x & 63;
    int i = blockIdx.x * 4 + wv;
    if (i >= NHALF) return;
    const float4* r1 = (const float4*)(h1 + (size_t)i * DIM);
    const float4* r2 = (const float4*)(h2 + (size_t)i * DIM);
    float4 a0 = r1[lane], a1 = r1[lane + 64];
    float4 b0 = r2[lane], b1 = r2[lane + 64];
    float s1 = a0.x*a0.x + a0.y*a0.y + a0.z*a0.z + a0.w*a0.w
             + a1.x*a1.x + a1.y*a1.y + a1.z*a1.z + a1.w*a1.w;
    float s2 = b0.x*b0.x + b0.y*b0.y + b0.z*b0.z + b0.w*b0.w
             + b1.x*b1.x + b1.y*b1.y + b1.z*b1.z + b1.w*b1.w;
    float s12 = a0.x*b0.x + a0.y*b0.y + a0.z*b0.z + a0.w*b0.w
              + a1.x*b1.x + a1.y*b1.y + a1.z*b1.z + a1.w*b1.w;
    #pragma unroll
    for (int m = 1; m < 64; m <<= 1) {
        s1  += __shfl_xor(s1, m);
        s2  += __shfl_xor(s2, m);
        s12 += __shfl_xor(s12, m);
    }
    if (lane == 0) {
        sq[i] = s1;
        sq[i + NHALF] = s2;
        float pd = s1 + s2 - 2.0f * s12;
        hp_d2[i] = pd;
        hp_d2[i + NHALF] = pd;
    }
}

// Tiled gram with fused row-min and col-min. Only the 528 upper-triangle
// 128x128 tiles are launched (triangular decode of blockIdx.x).
// 256 threads (16x16), 8x8 micro-tile. LDS k-major [32][128] with XOR
// swizzle r^(c4<<3) to make the transposed ds_write_b32s 2-way (free).
// A-frag: 2x ds_read_b128 (4 distinct banks groups, broadcast). B-frag:
// 8x ds_read_b32 strided cols (16 banks x 4-lane broadcast). Conflict-free.
__global__ __launch_bounds__(256) void pairmin_kernel(const float* __restrict__ h1,
                                                      const float* __restrict__ h2,
                                                      const float* __restrict__ sq,
                                                      unsigned int* __restrict__ minb) {
    // triangular decode: blockIdx.x -> (bi, bj), bi <= bj
    int t = blockIdx.x, bi = 0, rem = NTILE;
    while (t >= rem) { t -= rem; ++bi; --rem; }
    int bj = bi + t;

    __shared__ float As[BK][BM];    // 16 KB, [k][row^swz]
    __shared__ float Bs[BK][BM];    // 16 KB
    __shared__ float colbuf[BM][4]; // 2 KB

    int tid = threadIdx.x;
    int tx = tid & 15, ty = tid >> 4;
    int lane = tid & 63, wv = tid >> 6;

    int rowA0 = bi * BM, rowB0 = bj * BM;
    // each 128-row tile lies wholly inside h1 or h2 (128 | 2048)
    const float* baseA = (bi < NTILE / 2) ? (h1 + (size_t)rowA0 * DIM)
                                          : (h2 + (size_t)(rowA0 - NHALF) * DIM);
    const float* baseB = (bj < NTILE / 2) ? (h1 + (size_t)rowB0 * DIM)
                                          : (h2 + (size_t)(rowB0 - NHALF) * DIM);

    float acc[8][8];
    #pragma unroll
    for (int r = 0; r < 8; ++r)
        #pragma unroll
        for (int c = 0; c < 8; ++c) acc[r][c] = 0.0f;

    for (int kt = 0; kt < KTILES; ++kt) {
        int k0 = kt * BK;
        __syncthreads();
        // stage: 1024 float4 chunks per tile side; q -> (row, chunk)
        #pragma unroll
        for (int s = 0; s < 4; ++s) {
            int q = s * 256 + tid;
            int r = q >> 3;       // row in tile
            int c4 = q & 7;       // float4 chunk (k = c4*4+u)
            float4 va = *(const float4*)(baseA + (size_t)r * DIM + k0 + c4 * 4);
            float4 vb = *(const float4*)(baseB + (size_t)r * DIM + k0 + c4 * 4);
            int sw = r ^ (c4 << 3);
            As[c4 * 4 + 0][sw] = va.x;
            As[c4 * 4 + 1][sw] = va.y;
            As[c4 * 4 + 2][sw] = va.z;
            As[c4 * 4 + 3][sw] = va.w;
            Bs[c4 * 4 + 0][sw] = vb.x;
            Bs[c4 * 4 + 1][sw] = vb.y;
            Bs[c4 * 4 + 2][sw] = vb.z;
            Bs[c4 * 4 + 3][sw] = vb.w;
        }
        __syncthreads();
        #pragma unroll 4
        for (int kk = 0; kk < BK; ++kk) {
            int sk = (kk >> 2) & 7;
            const float* arow = &As[kk][0];
            const float* brow = &Bs[kk][0];
            int abase = ((ty ^ sk) << 3);
            float4 a0 = *(const float4*)(arow + abase);
            float4 a1 = *(const float4*)(arow + abase + 4);
            float ar[8] = {a0.x, a0.y, a0.z, a0.w, a1.x, a1.y, a1.z, a1.w};
            float bv[8];
            #pragma unroll
            for (int c = 0; c < 8; ++c)
                bv[c] = brow[(tx + (c << 4)) ^ (sk << 3)];
            #pragma unroll
            for (int r = 0; r < 8; ++r)
                #pragma unroll
                for (int c = 0; c < 8; ++c)
                    acc[r][c] = fmaf(ar[r], bv[c], acc[r][c]);
        }
    }

    // Epilogue: d2 = sq_i + sq_j - 2*dot; mask same-label ((i-j)%2048==0).
    float sqi[8], sqj[8];
    #pragma unroll
    for (int r = 0; r < 8; ++r) sqi[r] = sq[rowA0 + ty * 8 + r];
    #pragma unroll
    for (int c = 0; c < 8; ++c) sqj[c] = sq[rowB0 + tx + 16 * c];

    float rmin[8], cmin[8];
    #pragma unroll
    for (int r = 0; r < 8; ++r) rmin[r] = FLTMAX;
    #pragma unroll
    for (int c = 0; c < 8; ++c) cmin[c] = FLTMAX;

    #pragma unroll
    for (int r = 0; r < 8; ++r) {
        int gi = rowA0 + ty * 8 + r;
        #pragma unroll
        for (int c = 0; c < 8; ++c) {
            int gj = rowB0 + tx + 16 * c;
            float d2 = sqi[r] + sqj[c] - 2.0f * acc[r][c];
            d2 = fmaxf(d2, 0.0f);                              // keeps uint ordering
            if (((gi - gj) & (NHALF - 1)) == 0) d2 = FLTMAX;   // same label / diag
            rmin[r] = fminf(rmin[r], d2);
            cmin[c] = fminf(cmin[c], d2);
        }
    }

    // Row mins: reduce across tx (lane bits 0..3); tx==0 lanes commit.
    #pragma unroll
    for (int m = 1; m <= 8; m <<= 1) {
        #pragma unroll
        for (int r = 0; r < 8; ++r) rmin[r] = fminf(rmin[r], __shfl_xor(rmin[r], m));
    }
    if (tx == 0) {
        #pragma unroll
        for (int r = 0; r < 8; ++r)
            atomicMin(&minb[rowA0 + ty * 8 + r], __float_as_uint(rmin[r]));
    }

    // Col mins: reduce across ty-within-wave (lane bits 4,5), then cross-wave.
    #pragma unroll
    for (int m = 16; m <= 32; m <<= 1) {
        #pragma unroll
        for (int c = 0; c < 8; ++c) cmin[c] = fminf(cmin[c], __shfl_xor(cmin[c], m));
    }
    if (lane < 16) {
        #pragma unroll
        for (int c = 0; c < 8; ++c) colbuf[tx + 16 * c][wv] = cmin[c];
    }
    __syncthreads();
    if (tid < BM) {
        float m = fminf(fminf(colbuf[tid][0], colbuf[tid][1]),
                        fminf(colbuf[tid][2], colbuf[tid][3]));
        atomicMin(&minb[rowB0 + tid], __float_as_uint(m));
    }
}

__global__ __launch_bounds__(256) void finalize_kernel(const float* __restrict__ sq,
                                                       const float* __restrict__ hp_d2,
                                                       const unsigned int* __restrict__ minb,
                                                       float* __restrict__ out) {
    __shared__ float red[5][256];
    int tid = threadIdx.x;
    float sum_diff = 0.f, sum_rel = 0.f, sum_sq = 0.f, cnt_rel = 0.f, cnt_good = 0.f;
    for (int i = tid; i < NTOT; i += 256) {
        float hn = fmaxf(sqrtf(fmaxf(__uint_as_float(minb[i]), 1e-14f)), 1e-7f);
        float hp = fmaxf(sqrtf(fmaxf(hp_d2[i], 1e-14f)), 1e-7f);
        float diff = hp - hn;
        float t = fmaxf(diff + 0.1f, 0.0f);
        sum_diff += diff;
        sum_sq += sq[i];
        if (t < 1e-5f) cnt_good += 1.0f;
        if (t > 1e-5f) { cnt_rel += 1.0f; sum_rel += t; }
    }
    red[0][tid] = sum_diff; red[1][tid] = sum_rel; red[2][tid] = sum_sq;
    red[3][tid] = cnt_rel;  red[4][tid] = cnt_good;
    __syncthreads();
    for (int s = 128; s > 0; s >>= 1) {
        if (tid < s) {
            #pragma unroll
            for (int q = 0; q < 5; ++q) red[q][tid] += red[q][tid + s];
        }
        __syncthreads();
    }
    if (tid == 0) {
        float nrel = fmaxf(red[3][0], 1.0f);
        out[0] = red[1][0] / nrel;                 // loss (mean over relevant)
        out[1] = red[0][0] / (float)NTOT;          // mean(differences)
        out[2] = red[4][0];                        // good
        out[3] = (float)NTOT - red[4][0];          // bad
        out[4] = sqrtf(red[2][0] / (float)NTOT);   // sqrt(mean norm^2)
    }
}

extern "C" void kernel_launch(void* const* d_in, const int* in_sizes, int n_in,
                              void* d_out, int out_size, void* d_ws, size_t ws_size,
                              hipStream_t stream) {
    const float* h1 = (const float*)d_in[0];
    const float* h2 = (const float*)d_in[1];
    // d_in[2] (h3) is unused by the reference.

    float* sq = (float*)d_ws;                            // [4096]
    float* hp_d2 = sq + NTOT;                            // [4096]
    unsigned int* minb = (unsigned int*)(hp_d2 + NTOT);  // [4096]
    float* out = (float*)d_out;

    init_kernel<<<NTOT / 256, 256, 0, stream>>>(minb);
    rowstats_kernel<<<NHALF / 4, 256, 0, stream>>>(h1, h2, sq, hp_d2);
    pairmin_kernel<<<NTRI, 256, 0, stream>>>(h1, h2, sq, minb);
    finalize_kernel<<<1, 256, 0, stream>>>(sq, hp_d2, minb, out);
}

// Round 3
// 121.896 us; speedup vs baseline: 9.7653x; 1.8870x over previous
//
#include <hip/hip_runtime.h>
#include <hip/hip_bf16.h>
#include <float.h>
#include <math.h>

// BatchHardTripletLoss on MI355X — bf16x3 MFMA gram path.
// batch = concat(h1,h2) : [4096,512] fp32 -> hi/lo bf16 split.
// dot(a,b) ~= hi_a.hi_b + hi_a.lo_b + lo_a.hi_b  (fp32 MFMA accum)
// hardest_positive computed exactly in fp32 (prep), negatives via MFMA + fused min.

#define NTOT 4096
#define NHALF 2048
#define DIM 512
#define BM 128
#define BK 64                     // bf16 k-elems staged per step
#define KT_STEPS (DIM / BK)       // 8
#define NTILE (NTOT / BM)         // 32
#define NTRI (NTILE * (NTILE + 1) / 2)  // 528
#define FLTMAX 3.402823466e+38f

typedef __attribute__((ext_vector_type(8))) short bf16x8;
typedef __attribute__((ext_vector_type(4))) float f32x4;

#define GLLDS(gp, lp) __builtin_amdgcn_global_load_lds(                              \
    (const __attribute__((address_space(1))) void*)(gp),                             \
    (__attribute__((address_space(3))) void*)(lp), 16, 0, 0)

__device__ __forceinline__ ushort bf16hi_bits(float x, float* hf) {
    __hip_bfloat16 b = __float2bfloat16(x);
    *hf = __bfloat162float(b);
    return *reinterpret_cast<ushort*>(&b);
}
__device__ __forceinline__ ushort bf16_bits(float x) {
    __hip_bfloat16 b = __float2bfloat16(x);
    return *reinterpret_cast<ushort*>(&b);
}

// One wave per row-pair i: sq[i], sq[i+2048], exact partner d2, hi/lo bf16 split,
// and minb init. Fused to keep launch count at 3.
__global__ __launch_bounds__(256) void prep_kernel(const float* __restrict__ h1,
                                                   const float* __restrict__ h2,
                                                   float* __restrict__ sq,
                                                   float* __restrict__ hp_d2,
                                                   unsigned int* __restrict__ minb,
                                                   ushort* __restrict__ hi,
                                                   ushort* __restrict__ lo) {
    int wv = threadIdx.x >> 6, lane = threadIdx.x & 63;
    int i = blockIdx.x * 4 + wv;
    if (i >= NHALF) return;
    if (lane < 2) minb[i + lane * NHALF] = 0x7F800000u;  // +inf bits

    const float4* r1 = (const float4*)(h1 + (size_t)i * DIM);
    const float4* r2 = (const float4*)(h2 + (size_t)i * DIM);
    float4 a0 = r1[lane], a1 = r1[lane + 64];
    float4 b0 = r2[lane], b1 = r2[lane + 64];

    float s1 = a0.x*a0.x + a0.y*a0.y + a0.z*a0.z + a0.w*a0.w
             + a1.x*a1.x + a1.y*a1.y + a1.z*a1.z + a1.w*a1.w;
    float s2 = b0.x*b0.x + b0.y*b0.y + b0.z*b0.z + b0.w*b0.w
             + b1.x*b1.x + b1.y*b1.y + b1.z*b1.z + b1.w*b1.w;
    float s12 = a0.x*b0.x + a0.y*b0.y + a0.z*b0.z + a0.w*b0.w
              + a1.x*b1.x + a1.y*b1.y + a1.z*b1.z + a1.w*b1.w;

    // hi/lo split + stores (row i from h1, row i+2048 from h2)
    {
        float f[8] = {a0.x, a0.y, a0.z, a0.w, a1.x, a1.y, a1.z, a1.w};
        float g[8] = {b0.x, b0.y, b0.z, b0.w, b1.x, b1.y, b1.z, b1.w};
        ushort4 h4, l4v;
        float hf;
        // h1 row, first 4 (cols lane*4), then second 4 (cols 256+lane*4)
        #pragma unroll
        for (int half = 0; half < 2; ++half) {
            float* p = f + half * 4;
            h4.x = bf16hi_bits(p[0], &hf); l4v.x = bf16_bits(p[0] - hf);
            h4.y = bf16hi_bits(p[1], &hf); l4v.y = bf16_bits(p[1] - hf);
            h4.z = bf16hi_bits(p[2], &hf); l4v.z = bf16_bits(p[2] - hf);
            h4.w = bf16hi_bits(p[3], &hf); l4v.w = bf16_bits(p[3] - hf);
            size_t off = (size_t)i * DIM + half * 256 + lane * 4;
            *(ushort4*)(hi + off) = h4;
            *(ushort4*)(lo + off) = l4v;
        }
        #pragma unroll
        for (int half = 0; half < 2; ++half) {
            float* p = g + half * 4;
            h4.x = bf16hi_bits(p[0], &hf); l4v.x = bf16_bits(p[0] - hf);
            h4.y = bf16hi_bits(p[1], &hf); l4v.y = bf16_bits(p[1] - hf);
            h4.z = bf16hi_bits(p[2], &hf); l4v.z = bf16_bits(p[2] - hf);
            h4.w = bf16hi_bits(p[3], &hf); l4v.w = bf16_bits(p[3] - hf);
            size_t off = (size_t)(i + NHALF) * DIM + half * 256 + lane * 4;
            *(ushort4*)(hi + off) = h4;
            *(ushort4*)(lo + off) = l4v;
        }
    }

    #pragma unroll
    for (int m = 1; m < 64; m <<= 1) {
        s1  += __shfl_xor(s1, m);
        s2  += __shfl_xor(s2, m);
        s12 += __shfl_xor(s12, m);
    }
    if (lane == 0) {
        sq[i] = s1;
        sq[i + NHALF] = s2;
        float pd = s1 + s2 - 2.0f * s12;
        hp_d2[i] = pd;
        hp_d2[i + NHALF] = pd;
    }
}

// Triangular 128x128 tiles (528 blocks), 4 waves in 2x2, each wave 64x64 via
// 4x4 fragments of mfma_f32_16x16x32_bf16, 3 MFMA per fragment (hi*hi, hi*lo,
// lo*hi). LDS: 4 buffers [128][64] bf16 (Ahi,Alo,Bhi,Blo) = 64 KB, staged via
// global_load_lds width=16 with pre-swizzled global source (chunk ^= row&7) so
// frag ds_read_b128 spreads banks. Fused row/col min epilogue -> atomicMin.
__global__ __launch_bounds__(256, 2) void pairmin_mfma(const ushort* __restrict__ hi,
                                                       const ushort* __restrict__ lo,
                                                       const float* __restrict__ sq,
                                                       unsigned int* __restrict__ minb) {
    __shared__ ushort lds[4 * BM * BK] __attribute__((aligned(16)));

    int t = blockIdx.x, bi = 0, rem = NTILE;
    while (t >= rem) { t -= rem; ++bi; --rem; }
    int bj = bi + t;
    int rowA0 = bi * BM, rowB0 = bj * BM;

    int tid = threadIdx.x;
    int w = tid >> 6, lane = tid & 63;
    int wr = w >> 1, wc = w & 1;
    int l15 = lane & 15, l4 = lane >> 4;

    // Staging: wave w owns buffer w: 0=Ahi 1=Alo 2=Bhi 3=Blo.
    const ushort* gsrc = (w & 1) ? lo : hi;
    int grow0 = (w < 2) ? rowA0 : rowB0;
    int rloc = lane >> 3, cslot = lane & 7;
    int gchunk = cslot ^ rloc;  // row&7 == rloc for every 8-row group
    const ushort* gbase = gsrc + (size_t)(grow0 + rloc) * DIM + gchunk * 8;
    ushort* lwbase = &lds[w * (BM * BK)];

    f32x4 acc[4][4];
    #pragma unroll
    for (int m = 0; m < 4; ++m)
        #pragma unroll
        for (int n = 0; n < 4; ++n)
            acc[m][n] = (f32x4){0.f, 0.f, 0.f, 0.f};

    for (int kt = 0; kt < KT_STEPS; ++kt) {
        __syncthreads();  // previous k-step's frag reads done before overwrite
        const ushort* gk = gbase + kt * BK;
        #pragma unroll
        for (int tt = 0; tt < 16; ++tt)
            GLLDS(gk + (size_t)tt * 8 * DIM, lwbase + tt * 8 * BK);
        __syncthreads();  // drains vmcnt -> staged data visible

        #pragma unroll
        for (int ksl = 0; ksl < 2; ++ksl) {
            bf16x8 Ah[4], Al[4], Bh[4], Bl[4];
            #pragma unroll
            for (int m = 0; m < 4; ++m) {
                int row = wr * 64 + m * 16 + l15;
                int slot = (ksl * 4 + l4) ^ (row & 7);
                Ah[m] = *(const bf16x8*)&lds[0 * (BM * BK) + row * BK + slot * 8];
                Al[m] = *(const bf16x8*)&lds[1 * (BM * BK) + row * BK + slot * 8];
            }
            #pragma unroll
            for (int n = 0; n < 4; ++n) {
                int row = wc * 64 + n * 16 + l15;
                int slot = (ksl * 4 + l4) ^ (row & 7);
                Bh[n] = *(const bf16x8*)&lds[2 * (BM * BK) + row * BK + slot * 8];
                Bl[n] = *(const bf16x8*)&lds[3 * (BM * BK) + row * BK + slot * 8];
            }
            #pragma unroll
            for (int m = 0; m < 4; ++m)
                #pragma unroll
                for (int n = 0; n < 4; ++n) {
                    acc[m][n] = __builtin_amdgcn_mfma_f32_16x16x32_bf16(Ah[m], Bh[n], acc[m][n], 0, 0, 0);
                    acc[m][n] = __builtin_amdgcn_mfma_f32_16x16x32_bf16(Ah[m], Bl[n], acc[m][n], 0, 0, 0);
                    acc[m][n] = __builtin_amdgcn_mfma_f32_16x16x32_bf16(Al[m], Bh[n], acc[m][n], 0, 0, 0);
                }
        }
    }

    // Epilogue. C/D layout (m89-verified): col = lane&15, row = (lane>>4)*4 + reg.
    float cmin[4];
    float sqb_[4];
    #pragma unroll
    for (int n = 0; n < 4; ++n) {
        cmin[n] = FLTMAX;
        sqb_[n] = sq[rowB0 + wc * 64 + n * 16 + l15];
    }
    #pragma unroll
    for (int m = 0; m < 4; ++m) {
        #pragma unroll
        for (int r = 0; r < 4; ++r) {
            int gi = rowA0 + wr * 64 + m * 16 + l4 * 4 + r;
            float sa = sq[gi];
            float rm = FLTMAX;
            #pragma unroll
            for (int n = 0; n < 4; ++n) {
                int gj = rowB0 + wc * 64 + n * 16 + l15;
                float d2 = sa + sqb_[n] - 2.0f * acc[m][n][r];
                d2 = fmaxf(d2, 0.0f);                              // keep uint ordering
                if (((gi - gj) & (NHALF - 1)) == 0) d2 = FLTMAX;   // same label / diag
                rm = fminf(rm, d2);
                cmin[n] = fminf(cmin[n], d2);
            }
            rm = fminf(rm, __shfl_xor(rm, 1));
            rm = fminf(rm, __shfl_xor(rm, 2));
            rm = fminf(rm, __shfl_xor(rm, 4));
            rm = fminf(rm, __shfl_xor(rm, 8));
            if (l15 == 0) atomicMin(&minb[gi], __float_as_uint(rm));
        }
    }
    #pragma unroll
    for (int n = 0; n < 4; ++n) {
        cmin[n] = fminf(cmin[n], __shfl_xor(cmin[n], 16));
        cmin[n] = fminf(cmin[n], __shfl_xor(cmin[n], 32));
    }
    if (l4 == 0) {
        #pragma unroll
        for (int n = 0; n < 4; ++n)
            atomicMin(&minb[rowB0 + wc * 64 + n * 16 + l15], __float_as_uint(cmin[n]));
    }
}

__global__ __launch_bounds__(256) void finalize_kernel(const float* __restrict__ sq,
                                                       const float* __restrict__ hp_d2,
                                                       const unsigned int* __restrict__ minb,
                                                       float* __restrict__ out) {
    __shared__ float red[5][256];
    int tid = threadIdx.x;
    float sum_diff = 0.f, sum_rel = 0.f, sum_sq = 0.f, cnt_rel = 0.f, cnt_good = 0.f;
    for (int i = tid; i < NTOT; i += 256) {
        float hn = fmaxf(sqrtf(fmaxf(__uint_as_float(minb[i]), 1e-14f)), 1e-7f);
        float hp = fmaxf(sqrtf(fmaxf(hp_d2[i], 1e-14f)), 1e-7f);
        float diff = hp - hn;
        float tt = fmaxf(diff + 0.1f, 0.0f);
        sum_diff += diff;
        sum_sq += sq[i];
        if (tt < 1e-5f) cnt_good += 1.0f;
        if (tt > 1e-5f) { cnt_rel += 1.0f; sum_rel += tt; }
    }
    red[0][tid] = sum_diff; red[1][tid] = sum_rel; red[2][tid] = sum_sq;
    red[3][tid] = cnt_rel;  red[4][tid] = cnt_good;
    __syncthreads();
    for (int s = 128; s > 0; s >>= 1) {
        if (tid < s) {
            #pragma unroll
            for (int q = 0; q < 5; ++q) red[q][tid] += red[q][tid + s];
        }
        __syncthreads();
    }
    if (tid == 0) {
        float nrel = fmaxf(red[3][0], 1.0f);
        out[0] = red[1][0] / nrel;                 // loss (mean over relevant)
        out[1] = red[0][0] / (float)NTOT;          // mean(differences)
        out[2] = red[4][0];                        // good
        out[3] = (float)NTOT - red[4][0];          // bad
        out[4] = sqrtf(red[2][0] / (float)NTOT);   // sqrt(mean norm^2)
    }
}

extern "C" void kernel_launch(void* const* d_in, const int* in_sizes, int n_in,
                              void* d_out, int out_size, void* d_ws, size_t ws_size,
                              hipStream_t stream) {
    const float* h1 = (const float*)d_in[0];
    const float* h2 = (const float*)d_in[1];
    // d_in[2] (h3) unused by the reference.

    char* ws = (char*)d_ws;
    float* sq = (float*)ws;                                  // 16 KB
    float* hp_d2 = (float*)(ws + 16384);                     // 16 KB
    unsigned int* minb = (unsigned int*)(ws + 32768);        // 16 KB
    ushort* hi = (ushort*)(ws + 49152);                      // 4 MB
    ushort* lo = (ushort*)(ws + 49152 + (size_t)NTOT * DIM * 2);  // 4 MB
    float* out = (float*)d_out;

    prep_kernel<<<NHALF / 4, 256, 0, stream>>>(h1, h2, sq, hp_d2, minb, hi, lo);
    pairmin_mfma<<<NTRI, 256, 0, stream>>>(hi, lo, sq, minb);
    finalize_kernel<<<1, 256, 0, stream>>>(sq, hp_d2, minb, out);
}